// Round 4
// baseline (1355.908 us; speedup 1.0000x reference)
//
#include <hip/hip_runtime.h>

#define NCH 64

// ---------------- degree histogram ----------------
__global__ void hist_dst(const int* __restrict__ dst, int E, int* __restrict__ deg) {
    int i = blockIdx.x * blockDim.x + threadIdx.x;
    if (i < E) atomicAdd(&deg[dst[i]], 1);
}

// ---------------- 3-kernel exclusive scan over deg[n] ----------------
__global__ void scan1_blocksum(const int* __restrict__ deg, int n, int* __restrict__ bsum) {
    __shared__ int s[256];
    int t = threadIdx.x;
    int i = blockIdx.x * 256 + t;
    s[t] = (i < n) ? deg[i] : 0;
    __syncthreads();
    for (int o = 128; o > 0; o >>= 1) {
        if (t < o) s[t] += s[t + o];
        __syncthreads();
    }
    if (t == 0) bsum[blockIdx.x] = s[0];
}

__global__ void scan2_exclusive(int* __restrict__ bsum, int nb) {
    // single block of 512; nb <= 512
    __shared__ int s[512];
    int t = threadIdx.x;
    int v = (t < nb) ? bsum[t] : 0;
    s[t] = v;
    __syncthreads();
    for (int o = 1; o < 512; o <<= 1) {
        int x = (t >= o) ? s[t - o] : 0;
        __syncthreads();
        s[t] += x;
        __syncthreads();
    }
    if (t < nb) bsum[t] = s[t] - v;  // exclusive
}

__global__ void scan3_final(const int* __restrict__ deg, const int* __restrict__ bsum,
                            int n, int E, int* __restrict__ offsets,
                            int* __restrict__ cursor, float* __restrict__ dinv) {
    __shared__ int s[256];
    int t = threadIdx.x;
    int i = blockIdx.x * 256 + t;
    int v = (i < n) ? deg[i] : 0;
    s[t] = v;
    __syncthreads();
    for (int o = 1; o < 256; o <<= 1) {
        int x = (t >= o) ? s[t - o] : 0;
        __syncthreads();
        s[t] += x;
        __syncthreads();
    }
    int excl = s[t] - v + bsum[blockIdx.x];
    if (i < n) {
        offsets[i] = excl;
        cursor[i]  = excl;
        dinv[i]    = rsqrtf((float)v + 1.0f);  // +1 self-loop
    }
    if (i == n - 1) offsets[n] = E;
}

// ---------------- bucket fill: srcs[pos] = src  (4B records) ----------------
__global__ void fill_csr(const int* __restrict__ src, const int* __restrict__ dst, int E,
                         int* __restrict__ cursor, int* __restrict__ srcs) {
    int e = blockIdx.x * blockDim.x + threadIdx.x;
    if (e >= E) return;
    int s = src[e], d = dst[e];
    int pos = atomicAdd(&cursor[d], 1);
    srcs[pos] = s;
}

// ---------------- GEMM: Y[row,:] = (X[row,:] @ W) * dscale[row] ----------------
// 64 rows/block, 256 threads, 16 outputs/thread.
__global__ __launch_bounds__(256) void gemm64(const float* __restrict__ X,
                                              const float* __restrict__ W,
                                              const float* __restrict__ dscale,
                                              float* __restrict__ Y, int n) {
    __shared__ float Ws[64][64];   // 16 KB
    __shared__ float Xs[64][64];   // 16 KB
    int tid = threadIdx.x;
    const float4* W4 = (const float4*)W;
    float4* Ws4 = (float4*)Ws;
#pragma unroll
    for (int i = 0; i < 4; ++i) Ws4[tid + 256 * i] = W4[tid + 256 * i];

    int row0 = blockIdx.x * 64;
    float4* Xs4 = (float4*)Xs;
    const float4* X4 = (const float4*)(X + (size_t)row0 * NCH);
    if (row0 + 64 <= n) {
#pragma unroll
        for (int i = 0; i < 4; ++i) Xs4[tid + 256 * i] = X4[tid + 256 * i];
    } else {
#pragma unroll
        for (int i = 0; i < 4; ++i) {
            int idx = tid + 256 * i;
            int r = idx >> 4;  // 16 float4 per row
            float4 v = make_float4(0.f, 0.f, 0.f, 0.f);
            if (row0 + r < n) v = X4[idx];
            Xs4[idx] = v;
        }
    }
    __syncthreads();

    int c = tid & 63, rq = tid >> 6;  // this thread: col c, rows rq*16 .. rq*16+15
    float acc[16];
#pragma unroll
    for (int j = 0; j < 16; ++j) acc[j] = 0.f;

#pragma unroll
    for (int k = 0; k < 64; k += 4) {
        float w0 = Ws[k][c], w1 = Ws[k + 1][c], w2 = Ws[k + 2][c], w3 = Ws[k + 3][c];
#pragma unroll
        for (int j = 0; j < 16; ++j) {
            float4 xv = *(const float4*)&Xs[rq * 16 + j][k];
            acc[j] += xv.x * w0 + xv.y * w1 + xv.z * w2 + xv.w * w3;
        }
    }

#pragma unroll
    for (int j = 0; j < 16; ++j) {
        int row = row0 + rq * 16 + j;
        if (row < n) Y[(size_t)row * NCH + c] = acc[j] * dscale[row];
    }
}

// ---------------- CSR gather + self-loop + bias + relu, one wave per node ----------------
// XWs rows are pre-scaled by dinv[src]; out = dinv[d] * (self + sum) + b
__global__ __launch_bounds__(256) void gather_fused(const float* __restrict__ XWs,
                                                    const int* __restrict__ srcs,
                                                    const int* __restrict__ offsets,
                                                    const float* __restrict__ dinv,
                                                    const float* __restrict__ b,
                                                    float* __restrict__ H, int n) {
    int wid  = (int)((blockIdx.x * (size_t)blockDim.x + threadIdx.x) >> 6);  // node
    int lane = threadIdx.x & 63;                                             // channel
    if (wid >= n) return;
    int start = offsets[wid], end = offsets[wid + 1];
    float acc0 = XWs[(size_t)wid * NCH + lane];  // self-loop (already *dinv[wid])
    float acc1 = 0.f, acc2 = 0.f, acc3 = 0.f;
    int e = start;
    for (; e + 4 <= end; e += 4) {
        int s0 = srcs[e], s1 = srcs[e + 1], s2 = srcs[e + 2], s3 = srcs[e + 3];
        acc0 += XWs[(size_t)s0 * NCH + lane];
        acc1 += XWs[(size_t)s1 * NCH + lane];
        acc2 += XWs[(size_t)s2 * NCH + lane];
        acc3 += XWs[(size_t)s3 * NCH + lane];
    }
    for (; e < end; ++e) {
        int s0 = srcs[e];
        acc0 += XWs[(size_t)s0 * NCH + lane];
    }
    float v = (acc0 + acc1 + acc2 + acc3) * dinv[wid] + b[lane];
    H[(size_t)wid * NCH + lane] = v > 0.0f ? v : 0.0f;
}

// ---------------- mean-pool per graph + FC + relu ----------------
__global__ __launch_bounds__(256) void pool_fc(const float* __restrict__ H,
                                               const int* __restrict__ batch, int n,
                                               const float* __restrict__ Wfc,
                                               const float* __restrict__ bfc,
                                               float* __restrict__ out) {
    int g = blockIdx.x;
    int lo = 0, hi = n;
    while (lo < hi) { int m = (lo + hi) >> 1; if (batch[m] < g) lo = m + 1; else hi = m; }
    int start = lo;
    hi = n;
    while (lo < hi) { int m = (lo + hi) >> 1; if (batch[m] < g + 1) lo = m + 1; else hi = m; }
    int end = lo;
    int count = end - start;

    int sub = threadIdx.x >> 6, c = threadIdx.x & 63;
    float acc = 0.0f;
    for (int i = start + sub; i < end; i += 4) acc += H[(size_t)i * NCH + c];

    __shared__ float part[4][64];
    __shared__ float pooled[64];
    part[sub][c] = acc;
    __syncthreads();
    if (threadIdx.x < 64) {
        float s = part[0][c] + part[1][c] + part[2][c] + part[3][c];
        pooled[c] = s / (float)(count > 1 ? count : 1);
    }
    __syncthreads();
    if (threadIdx.x < 64) {
        float acc2 = bfc[c];
#pragma unroll
        for (int k = 0; k < 64; ++k) acc2 += pooled[k] * Wfc[k * NCH + c];
        out[(size_t)g * NCH + c] = acc2 > 0.0f ? acc2 : 0.0f;
    }
}

static inline size_t align256(size_t x) { return (x + 255) & ~(size_t)255; }

extern "C" void kernel_launch(void* const* d_in, const int* in_sizes, int n_in,
                              void* d_out, int out_size, void* d_ws, size_t ws_size,
                              hipStream_t stream) {
    const float* x     = (const float*)d_in[0];
    const int*   ei    = (const int*)d_in[1];
    const int*   batch = (const int*)d_in[2];
    const float* W1    = (const float*)d_in[3];
    const float* b1    = (const float*)d_in[4];
    const float* W2    = (const float*)d_in[5];
    const float* b2    = (const float*)d_in[6];
    const float* Wfc   = (const float*)d_in[7];
    const float* bfc   = (const float*)d_in[8];
    float* out = (float*)d_out;

    int E = in_sizes[1] / 2;
    int n = in_sizes[0] / NCH;
    const int* src = ei;
    const int* dst = ei + E;

    char* p = (char*)d_ws;
    int*   deg     = (int*)p;   p += align256((size_t)n * 4);
    int*   cursor  = (int*)p;   p += align256((size_t)n * 4);
    int*   offsets = (int*)p;   p += align256((size_t)(n + 1) * 4);
    float* dinv    = (float*)p; p += align256((size_t)n * 4);
    int*   bsum    = (int*)p;   p += align256((size_t)1024 * 4);
    int*   srcs    = (int*)p;   p += align256((size_t)E * 4);
    float* xw      = (float*)p; p += align256((size_t)n * NCH * 4);
    float* h       = (float*)p;

    int nb = (n + 255) / 256;

    // ---- CSR build (shared by both layers) ----
    hipMemsetAsync(deg, 0, (size_t)n * sizeof(int), stream);
    hist_dst<<<(E + 255) / 256, 256, 0, stream>>>(dst, E, deg);
    scan1_blocksum<<<nb, 256, 0, stream>>>(deg, n, bsum);
    scan2_exclusive<<<1, 512, 0, stream>>>(bsum, nb);
    scan3_final<<<nb, 256, 0, stream>>>(deg, bsum, n, E, offsets, cursor, dinv);
    fill_csr<<<(E + 255) / 256, 256, 0, stream>>>(src, dst, E, cursor, srcs);

    int gemm_blocks = (n + 63) / 64;

    // ---- layer 1 ----
    gemm64<<<gemm_blocks, 256, 0, stream>>>(x, W1, dinv, xw, n);
    gather_fused<<<(n * NCH + 255) / 256, 256, 0, stream>>>(xw, srcs, offsets, dinv, b1, h, n);

    // ---- layer 2 ----
    gemm64<<<gemm_blocks, 256, 0, stream>>>(h, W2, dinv, xw, n);
    gather_fused<<<(n * NCH + 255) / 256, 256, 0, stream>>>(xw, srcs, offsets, dinv, b2, h, n);

    // ---- pool + fc ----
    pool_fc<<<128, 256, 0, stream>>>(h, batch, n, Wfc, bfc, out);
}

// Round 5
// 495.716 us; speedup vs baseline: 2.7353x; 2.7353x over previous
//
#include <hip/hip_runtime.h>

#define NCH 64
#define RPW 8   // rows per wave in gemm64

// ---------------- degree histogram ----------------
__global__ void hist_dst(const int* __restrict__ dst, int E, int* __restrict__ deg) {
    int i = blockIdx.x * blockDim.x + threadIdx.x;
    if (i < E) atomicAdd(&deg[dst[i]], 1);
}

// ---------------- 3-kernel exclusive scan over deg[n] ----------------
__global__ void scan1_blocksum(const int* __restrict__ deg, int n, int* __restrict__ bsum) {
    __shared__ int s[256];
    int t = threadIdx.x;
    int i = blockIdx.x * 256 + t;
    s[t] = (i < n) ? deg[i] : 0;
    __syncthreads();
    for (int o = 128; o > 0; o >>= 1) {
        if (t < o) s[t] += s[t + o];
        __syncthreads();
    }
    if (t == 0) bsum[blockIdx.x] = s[0];
}

__global__ void scan2_exclusive(int* __restrict__ bsum, int nb) {
    __shared__ int s[512];
    int t = threadIdx.x;
    int v = (t < nb) ? bsum[t] : 0;
    s[t] = v;
    __syncthreads();
    for (int o = 1; o < 512; o <<= 1) {
        int x = (t >= o) ? s[t - o] : 0;
        __syncthreads();
        s[t] += x;
        __syncthreads();
    }
    if (t < nb) bsum[t] = s[t] - v;  // exclusive
}

__global__ void scan3_final(const int* __restrict__ deg, const int* __restrict__ bsum,
                            int n, int E, int* __restrict__ offsets,
                            int* __restrict__ cursor, float* __restrict__ dinv) {
    __shared__ int s[256];
    int t = threadIdx.x;
    int i = blockIdx.x * 256 + t;
    int v = (i < n) ? deg[i] : 0;
    s[t] = v;
    __syncthreads();
    for (int o = 1; o < 256; o <<= 1) {
        int x = (t >= o) ? s[t - o] : 0;
        __syncthreads();
        s[t] += x;
        __syncthreads();
    }
    int excl = s[t] - v + bsum[blockIdx.x];
    if (i < n) {
        offsets[i] = excl;
        cursor[i]  = excl;
        dinv[i]    = rsqrtf((float)v + 1.0f);  // +1 self-loop
    }
    if (i == n - 1) offsets[n] = E;
}

// ---------------- bucket fill: srcs[pos] = src  (4B records) ----------------
__global__ void fill_csr(const int* __restrict__ src, const int* __restrict__ dst, int E,
                         int* __restrict__ cursor, int* __restrict__ srcs) {
    int e = blockIdx.x * blockDim.x + threadIdx.x;
    if (e >= E) return;
    int s = src[e], d = dst[e];
    int pos = atomicAdd(&cursor[d], 1);
    srcs[pos] = s;
}

// ---------------- GEMM: Y[row,:] = (X[row,:] @ W) * dscale[row] ----------------
// One wave = 64 output columns. W column held in registers (wk[64]).
// X rows read via wave-uniform loads (scalar path) — no LDS, no sync.
// 4 waves/block, RPW rows per wave => 32 rows/block.
__global__ __launch_bounds__(256) void gemm64(const float* __restrict__ X,
                                              const float* __restrict__ W,
                                              const float* __restrict__ dscale,
                                              float* __restrict__ Y, int n) {
    int lane = threadIdx.x & 63;
    int wv   = __builtin_amdgcn_readfirstlane(threadIdx.x >> 6);
    int row0 = blockIdx.x * (4 * RPW) + wv * RPW;

    float wk[NCH];
#pragma unroll
    for (int k = 0; k < NCH; ++k) wk[k] = W[k * NCH + lane];

#pragma unroll 1
    for (int j = 0; j < RPW; ++j) {
        int row = row0 + j;
        if (row >= n) break;
        const float4* xr = (const float4*)(X + (size_t)row * NCH);
        float a0 = 0.f, a1 = 0.f, a2 = 0.f, a3 = 0.f;
#pragma unroll
        for (int kc = 0; kc < 16; kc += 4) {
            float4 v0 = xr[kc + 0];
            float4 v1 = xr[kc + 1];
            float4 v2 = xr[kc + 2];
            float4 v3 = xr[kc + 3];
            a0 += v0.x * wk[4*kc + 0] + v0.y * wk[4*kc + 1] + v0.z * wk[4*kc + 2] + v0.w * wk[4*kc + 3];
            a1 += v1.x * wk[4*kc + 4] + v1.y * wk[4*kc + 5] + v1.z * wk[4*kc + 6] + v1.w * wk[4*kc + 7];
            a2 += v2.x * wk[4*kc + 8] + v2.y * wk[4*kc + 9] + v2.z * wk[4*kc +10] + v2.w * wk[4*kc +11];
            a3 += v3.x * wk[4*kc +12] + v3.y * wk[4*kc +13] + v3.z * wk[4*kc +14] + v3.w * wk[4*kc +15];
        }
        float a = (a0 + a1) + (a2 + a3);
        Y[(size_t)row * NCH + lane] = a * dscale[row];
    }
}

// ---------------- CSR gather + self-loop + bias + relu, one wave per node ----------------
// XWs rows are pre-scaled by dinv[src]; out = dinv[d] * (self + sum) + b
__global__ __launch_bounds__(256) void gather_fused(const float* __restrict__ XWs,
                                                    const int* __restrict__ srcs,
                                                    const int* __restrict__ offsets,
                                                    const float* __restrict__ dinv,
                                                    const float* __restrict__ b,
                                                    float* __restrict__ H, int n) {
    int wid  = (int)((blockIdx.x * (size_t)blockDim.x + threadIdx.x) >> 6);  // node
    int lane = threadIdx.x & 63;                                             // channel
    if (wid >= n) return;
    int start = offsets[wid], end = offsets[wid + 1];
    float acc0 = XWs[(size_t)wid * NCH + lane];  // self-loop (already *dinv[wid])
    float acc1 = 0.f, acc2 = 0.f, acc3 = 0.f;
    int e = start;
    for (; e + 4 <= end; e += 4) {
        int s0 = srcs[e], s1 = srcs[e + 1], s2 = srcs[e + 2], s3 = srcs[e + 3];
        acc0 += XWs[(size_t)s0 * NCH + lane];
        acc1 += XWs[(size_t)s1 * NCH + lane];
        acc2 += XWs[(size_t)s2 * NCH + lane];
        acc3 += XWs[(size_t)s3 * NCH + lane];
    }
    for (; e < end; ++e) {
        int s0 = srcs[e];
        acc0 += XWs[(size_t)s0 * NCH + lane];
    }
    float v = (acc0 + acc1 + acc2 + acc3) * dinv[wid] + b[lane];
    H[(size_t)wid * NCH + lane] = v > 0.0f ? v : 0.0f;
}

// ---------------- mean-pool per graph + FC + relu ----------------
__global__ __launch_bounds__(256) void pool_fc(const float* __restrict__ H,
                                               const int* __restrict__ batch, int n,
                                               const float* __restrict__ Wfc,
                                               const float* __restrict__ bfc,
                                               float* __restrict__ out) {
    int g = blockIdx.x;
    int lo = 0, hi = n;
    while (lo < hi) { int m = (lo + hi) >> 1; if (batch[m] < g) lo = m + 1; else hi = m; }
    int start = lo;
    hi = n;
    while (lo < hi) { int m = (lo + hi) >> 1; if (batch[m] < g + 1) lo = m + 1; else hi = m; }
    int end = lo;
    int count = end - start;

    int sub = threadIdx.x >> 6, c = threadIdx.x & 63;
    float acc = 0.0f;
    for (int i = start + sub; i < end; i += 4) acc += H[(size_t)i * NCH + c];

    __shared__ float part[4][64];
    __shared__ float pooled[64];
    part[sub][c] = acc;
    __syncthreads();
    if (threadIdx.x < 64) {
        float s = part[0][c] + part[1][c] + part[2][c] + part[3][c];
        pooled[c] = s / (float)(count > 1 ? count : 1);
    }
    __syncthreads();
    if (threadIdx.x < 64) {
        float acc2 = bfc[c];
#pragma unroll
        for (int k = 0; k < 64; ++k) acc2 += pooled[k] * Wfc[k * NCH + c];
        out[(size_t)g * NCH + c] = acc2 > 0.0f ? acc2 : 0.0f;
    }
}

static inline size_t align256(size_t x) { return (x + 255) & ~(size_t)255; }

extern "C" void kernel_launch(void* const* d_in, const int* in_sizes, int n_in,
                              void* d_out, int out_size, void* d_ws, size_t ws_size,
                              hipStream_t stream) {
    const float* x     = (const float*)d_in[0];
    const int*   ei    = (const int*)d_in[1];
    const int*   batch = (const int*)d_in[2];
    const float* W1    = (const float*)d_in[3];
    const float* b1    = (const float*)d_in[4];
    const float* W2    = (const float*)d_in[5];
    const float* b2    = (const float*)d_in[6];
    const float* Wfc   = (const float*)d_in[7];
    const float* bfc   = (const float*)d_in[8];
    float* out = (float*)d_out;

    int E = in_sizes[1] / 2;
    int n = in_sizes[0] / NCH;
    const int* src = ei;
    const int* dst = ei + E;

    char* p = (char*)d_ws;
    int*   deg     = (int*)p;   p += align256((size_t)n * 4);
    int*   cursor  = (int*)p;   p += align256((size_t)n * 4);
    int*   offsets = (int*)p;   p += align256((size_t)(n + 1) * 4);
    float* dinv    = (float*)p; p += align256((size_t)n * 4);
    int*   bsum    = (int*)p;   p += align256((size_t)1024 * 4);
    int*   srcs    = (int*)p;   p += align256((size_t)E * 4);
    float* xw      = (float*)p; p += align256((size_t)n * NCH * 4);
    float* h       = (float*)p;

    int nb = (n + 255) / 256;

    // ---- CSR build (shared by both layers) ----
    hipMemsetAsync(deg, 0, (size_t)n * sizeof(int), stream);
    hist_dst<<<(E + 255) / 256, 256, 0, stream>>>(dst, E, deg);
    scan1_blocksum<<<nb, 256, 0, stream>>>(deg, n, bsum);
    scan2_exclusive<<<1, 512, 0, stream>>>(bsum, nb);
    scan3_final<<<nb, 256, 0, stream>>>(deg, bsum, n, E, offsets, cursor, dinv);
    fill_csr<<<(E + 255) / 256, 256, 0, stream>>>(src, dst, E, cursor, srcs);

    int rows_per_block = 4 * RPW;  // 32
    int gemm_blocks = (n + rows_per_block - 1) / rows_per_block;

    // ---- layer 1 ----
    gemm64<<<gemm_blocks, 256, 0, stream>>>(x, W1, dinv, xw, n);
    gather_fused<<<(n * NCH + 255) / 256, 256, 0, stream>>>(xw, srcs, offsets, dinv, b1, h, n);

    // ---- layer 2 ----
    gemm64<<<gemm_blocks, 256, 0, stream>>>(h, W2, dinv, xw, n);
    gather_fused<<<(n * NCH + 255) / 256, 256, 0, stream>>>(xw, srcs, offsets, dinv, b2, h, n);

    // ---- pool + fc ----
    pool_fc<<<128, 256, 0, stream>>>(h, batch, n, Wfc, bfc, out);
}

// Round 8
// 366.698 us; speedup vs baseline: 3.6976x; 1.3518x over previous
//
#include <hip/hip_runtime.h>
#include <hip/hip_fp16.h>

#define NCH 64
#define RPW 8      // rows per wave in gemm64
#define MAXB 512   // max buckets (supports n <= 131072)
#define CHUNK 4096 // edges per block in hist/scatter

// ---------------- A: bucket histogram (bucket = dst >> 8) ----------------
__global__ __launch_bounds__(256) void bucket_hist(const int* __restrict__ dst, int E,
                                                   int NB, int* __restrict__ bhist) {
    __shared__ int lh[MAXB];
    int t = threadIdx.x;
    for (int i = t; i < NB; i += 256) lh[i] = 0;
    __syncthreads();
    int base = blockIdx.x * CHUNK;
    int end = min(base + CHUNK, E);
    for (int i = base + t; i < end; i += 256)
        atomicAdd(&lh[dst[i] >> 8], 1);
    __syncthreads();
    for (int i = t; i < NB; i += 256) {
        int v = lh[i];
        if (v) atomicAdd(&bhist[i], v);
    }
}

// ---------------- B: exclusive scan of bucket counts (1 block) ----------------
__global__ __launch_bounds__(MAXB) void bucket_scan(const int* __restrict__ bhist, int NB,
                                                    int* __restrict__ bbase,
                                                    int* __restrict__ bcursor) {
    __shared__ int s[MAXB];
    int t = threadIdx.x;
    int v = (t < NB) ? bhist[t] : 0;
    s[t] = v;
    __syncthreads();
    for (int o = 1; o < MAXB; o <<= 1) {
        int x = (t >= o) ? s[t - o] : 0;
        __syncthreads();
        s[t] += x;
        __syncthreads();
    }
    int excl = s[t] - v;
    if (t < NB) { bbase[t] = excl; bcursor[t] = excl; }
    if (t == NB - 1) bbase[NB] = s[t];  // = E
}

// ---------------- C: scatter (src,dst) pairs into bucket-grouped tmp ----------------
// Per-block LDS histogram + one global reservation per (block,bucket) keeps
// global atomics ~10x down and writes dense within each bucket stream.
__global__ __launch_bounds__(256) void bucket_scatter(const int* __restrict__ src,
                                                      const int* __restrict__ dst, int E,
                                                      int NB, int* __restrict__ bcursor,
                                                      int2* __restrict__ tmp) {
    __shared__ int lh[MAXB];
    __shared__ int lbase[MAXB];
    int t = threadIdx.x;
    for (int i = t; i < NB; i += 256) lh[i] = 0;
    __syncthreads();
    int base = blockIdx.x * CHUNK;
    int end = min(base + CHUNK, E);
    for (int i = base + t; i < end; i += 256)
        atomicAdd(&lh[dst[i] >> 8], 1);
    __syncthreads();
    for (int i = t; i < NB; i += 256) {
        int v = lh[i];
        lbase[i] = v ? atomicAdd(&bcursor[i], v) : 0;
        lh[i] = 0;  // reuse as local cursor
    }
    __syncthreads();
    for (int i = base + t; i < end; i += 256) {
        int s_ = src[i], d_ = dst[i];
        int b = d_ >> 8;
        int p = lbase[b] + atomicAdd(&lh[b], 1);
        tmp[p] = make_int2(s_, d_);
    }
}

// ---------------- D: per-bucket finalize: local CSR + dinv + srcs ----------------
__global__ __launch_bounds__(256) void bucket_finalize(const int2* __restrict__ tmp,
                                                       const int* __restrict__ bbase,
                                                       int n, int E, int NB,
                                                       int* __restrict__ offsets,
                                                       float* __restrict__ dinv,
                                                       int* __restrict__ srcs) {
    int b = blockIdx.x;
    int t = threadIdx.x;
    __shared__ int ldeg[256];
    __shared__ int lsc[256];
    __shared__ int lcur[256];
    ldeg[t] = 0;
    __syncthreads();
    int s0 = bbase[b], e0 = bbase[b + 1];
    for (int e = s0 + t; e < e0; e += 256)
        atomicAdd(&ldeg[tmp[e].y & 255], 1);
    __syncthreads();
    int v = ldeg[t];
    lsc[t] = v;
    __syncthreads();
    for (int o = 1; o < 256; o <<= 1) {
        int x = (t >= o) ? lsc[t - o] : 0;
        __syncthreads();
        lsc[t] += x;
        __syncthreads();
    }
    int excl = lsc[t] - v;
    lcur[t] = excl;
    int node = (b << 8) + t;
    if (node < n) {
        offsets[node] = s0 + excl;
        dinv[node] = rsqrtf((float)v + 1.0f);  // +1 self-loop
    }
    if (b == NB - 1 && t == 0) offsets[n] = E;
    __syncthreads();
    for (int e = s0 + t; e < e0; e += 256) {
        int2 r = tmp[e];
        int p = s0 + atomicAdd(&lcur[r.y & 255], 1);
        srcs[p] = r.x;
    }
}

// ---------------- GEMM: Yh[row,:] = half((X[row,:] @ W) * dscale[row]) ----------------
// One wave = 64 output columns. W column in registers; X rows via wave-uniform loads.
__global__ __launch_bounds__(256) void gemm64(const float* __restrict__ X,
                                              const float* __restrict__ W,
                                              const float* __restrict__ dscale,
                                              __half* __restrict__ Y, int n) {
    int lane = threadIdx.x & 63;
    int wv   = __builtin_amdgcn_readfirstlane(threadIdx.x >> 6);
    int row0 = blockIdx.x * (4 * RPW) + wv * RPW;

    float wk[NCH];
#pragma unroll
    for (int k = 0; k < NCH; ++k) wk[k] = W[k * NCH + lane];

#pragma unroll 1
    for (int j = 0; j < RPW; ++j) {
        int row = row0 + j;
        if (row >= n) break;
        const float4* xr = (const float4*)(X + (size_t)row * NCH);
        float a0 = 0.f, a1 = 0.f, a2 = 0.f, a3 = 0.f;
#pragma unroll
        for (int kc = 0; kc < 16; kc += 4) {
            float4 v0 = xr[kc + 0];
            float4 v1 = xr[kc + 1];
            float4 v2 = xr[kc + 2];
            float4 v3 = xr[kc + 3];
            a0 += v0.x * wk[4*kc + 0] + v0.y * wk[4*kc + 1] + v0.z * wk[4*kc + 2] + v0.w * wk[4*kc + 3];
            a1 += v1.x * wk[4*kc + 4] + v1.y * wk[4*kc + 5] + v1.z * wk[4*kc + 6] + v1.w * wk[4*kc + 7];
            a2 += v2.x * wk[4*kc + 8] + v2.y * wk[4*kc + 9] + v2.z * wk[4*kc +10] + v2.w * wk[4*kc +11];
            a3 += v3.x * wk[4*kc +12] + v3.y * wk[4*kc +13] + v3.z * wk[4*kc +14] + v3.w * wk[4*kc +15];
        }
        float a = (a0 + a1) + (a2 + a3);
        Y[(size_t)row * NCH + lane] = __float2half(a * dscale[row]);
    }
}

// ---------------- CSR gather (fp16 table) + self-loop + bias + relu ----------------
// XWs rows pre-scaled by dinv[src]; out = dinv[d] * (self + sum) + b
__global__ __launch_bounds__(256) void gather_fused(const __half* __restrict__ XWs,
                                                    const int* __restrict__ srcs,
                                                    const int* __restrict__ offsets,
                                                    const float* __restrict__ dinv,
                                                    const float* __restrict__ b,
                                                    float* __restrict__ H, int n) {
    int wid  = (int)((blockIdx.x * (size_t)blockDim.x + threadIdx.x) >> 6);  // node
    int lane = threadIdx.x & 63;                                             // channel
    if (wid >= n) return;
    int start = offsets[wid], end = offsets[wid + 1];
    float acc0 = __half2float(XWs[wid * NCH + lane]);  // self-loop (already *dinv[wid])
    float acc1 = 0.f, acc2 = 0.f, acc3 = 0.f;
    int e = start;
    for (; e + 4 <= end; e += 4) {
        int s0 = srcs[e], s1 = srcs[e + 1], s2 = srcs[e + 2], s3 = srcs[e + 3];
        acc0 += __half2float(XWs[s0 * NCH + lane]);
        acc1 += __half2float(XWs[s1 * NCH + lane]);
        acc2 += __half2float(XWs[s2 * NCH + lane]);
        acc3 += __half2float(XWs[s3 * NCH + lane]);
    }
    for (; e < end; ++e) {
        int s0 = srcs[e];
        acc0 += __half2float(XWs[s0 * NCH + lane]);
    }
    float v = (acc0 + acc1) + (acc2 + acc3);
    v = v * dinv[wid] + b[lane];
    H[(size_t)wid * NCH + lane] = v > 0.0f ? v : 0.0f;
}

// ---------------- mean-pool per graph + FC + relu ----------------
__global__ __launch_bounds__(256) void pool_fc(const float* __restrict__ H,
                                               const int* __restrict__ batch, int n,
                                               const float* __restrict__ Wfc,
                                               const float* __restrict__ bfc,
                                               float* __restrict__ out) {
    int g = blockIdx.x;
    int lo = 0, hi = n;
    while (lo < hi) { int m = (lo + hi) >> 1; if (batch[m] < g) lo = m + 1; else hi = m; }
    int start = lo;
    hi = n;
    while (lo < hi) { int m = (lo + hi) >> 1; if (batch[m] < g + 1) lo = m + 1; else hi = m; }
    int end = lo;
    int count = end - start;

    int sub = threadIdx.x >> 6, c = threadIdx.x & 63;
    float acc = 0.0f;
    for (int i = start + sub; i < end; i += 4) acc += H[(size_t)i * NCH + c];

    __shared__ float part[4][64];
    __shared__ float pooled[64];
    part[sub][c] = acc;
    __syncthreads();
    if (threadIdx.x < 64) {
        float s = part[0][c] + part[1][c] + part[2][c] + part[3][c];
        pooled[c] = s / (float)(count > 1 ? count : 1);
    }
    __syncthreads();
    if (threadIdx.x < 64) {
        float acc2 = bfc[c];
#pragma unroll
        for (int k = 0; k < 64; ++k) acc2 += pooled[k] * Wfc[k * NCH + c];
        out[(size_t)g * NCH + c] = acc2 > 0.0f ? acc2 : 0.0f;
    }
}

static inline size_t align256(size_t x) { return (x + 255) & ~(size_t)255; }

extern "C" void kernel_launch(void* const* d_in, const int* in_sizes, int n_in,
                              void* d_out, int out_size, void* d_ws, size_t ws_size,
                              hipStream_t stream) {
    const float* x     = (const float*)d_in[0];
    const int*   ei    = (const int*)d_in[1];
    const int*   batch = (const int*)d_in[2];
    const float* W1    = (const float*)d_in[3];
    const float* b1    = (const float*)d_in[4];
    const float* W2    = (const float*)d_in[5];
    const float* b2    = (const float*)d_in[6];
    const float* Wfc   = (const float*)d_in[7];
    const float* bfc   = (const float*)d_in[8];
    float* out = (float*)d_out;

    int E = in_sizes[1] / 2;
    int n = in_sizes[0] / NCH;
    const int* src = ei;
    const int* dst = ei + E;
    int NB = (n + 255) >> 8;

    char* p = (char*)d_ws;
    int*    bhist   = (int*)p;    p += align256((size_t)(MAXB + 1) * 4);
    int*    bbase   = (int*)p;    p += align256((size_t)(MAXB + 1) * 4);
    int*    bcursor = (int*)p;    p += align256((size_t)MAXB * 4);
    int*    offsets = (int*)p;    p += align256((size_t)(n + 1) * 4);
    float*  dinv    = (float*)p;  p += align256((size_t)n * 4);
    int2*   tmp     = (int2*)p;   p += align256((size_t)E * 8);
    int*    srcs    = (int*)p;    p += align256((size_t)E * 4);
    __half* xwh     = (__half*)p; p += align256((size_t)n * NCH * 2);
    float*  h       = (float*)p;

    int eblocks = (E + CHUNK - 1) / CHUNK;

    // ---- CSR build via 2-level bucket sort (shared by both layers) ----
    hipMemsetAsync(bhist, 0, (size_t)NB * sizeof(int), stream);
    bucket_hist<<<eblocks, 256, 0, stream>>>(dst, E, NB, bhist);
    bucket_scan<<<1, MAXB, 0, stream>>>(bhist, NB, bbase, bcursor);
    bucket_scatter<<<eblocks, 256, 0, stream>>>(src, dst, E, NB, bcursor, tmp);
    bucket_finalize<<<NB, 256, 0, stream>>>(tmp, bbase, n, E, NB, offsets, dinv, srcs);

    int rows_per_block = 4 * RPW;  // 32
    int gemm_blocks = (n + rows_per_block - 1) / rows_per_block;

    // ---- layer 1 ----
    gemm64<<<gemm_blocks, 256, 0, stream>>>(x, W1, dinv, xwh, n);
    gather_fused<<<(n * NCH + 255) / 256, 256, 0, stream>>>(xwh, srcs, offsets, dinv, b1, h, n);

    // ---- layer 2 ----
    gemm64<<<gemm_blocks, 256, 0, stream>>>(h, W2, dinv, xwh, n);
    gather_fused<<<(n * NCH + 255) / 256, 256, 0, stream>>>(xwh, srcs, offsets, dinv, b2, h, n);

    // ---- pool + fc ----
    pool_fc<<<128, 256, 0, stream>>>(h, batch, n, Wfc, bfc, out);
}

// Round 9
// 328.772 us; speedup vs baseline: 4.1242x; 1.1154x over previous
//
#include <hip/hip_runtime.h>
#include <hip/hip_fp16.h>

#define NCH 64
#define RPW 8      // rows per wave in gemm64
#define MAXB 512   // max buckets (supports n <= 131072)
#define CHUNK 4096 // edges per block in hist/scatter
#define POOL_BLOCKS 2048

// ---------------- A: bucket histogram (bucket = dst >> 8) ----------------
__global__ __launch_bounds__(256) void bucket_hist(const int* __restrict__ dst, int E,
                                                   int NB, int* __restrict__ bhist) {
    __shared__ int lh[MAXB];
    int t = threadIdx.x;
    for (int i = t; i < NB; i += 256) lh[i] = 0;
    __syncthreads();
    int base = blockIdx.x * CHUNK;
    int end = min(base + CHUNK, E);
    for (int i = base + t; i < end; i += 256)
        atomicAdd(&lh[dst[i] >> 8], 1);
    __syncthreads();
    for (int i = t; i < NB; i += 256) {
        int v = lh[i];
        if (v) atomicAdd(&bhist[i], v);
    }
}

// ---------------- B: exclusive scan of bucket counts (1 block) ----------------
__global__ __launch_bounds__(MAXB) void bucket_scan(const int* __restrict__ bhist, int NB,
                                                    int* __restrict__ bbase,
                                                    int* __restrict__ bcursor) {
    __shared__ int s[MAXB];
    int t = threadIdx.x;
    int v = (t < NB) ? bhist[t] : 0;
    s[t] = v;
    __syncthreads();
    for (int o = 1; o < MAXB; o <<= 1) {
        int x = (t >= o) ? s[t - o] : 0;
        __syncthreads();
        s[t] += x;
        __syncthreads();
    }
    int excl = s[t] - v;
    if (t < NB) { bbase[t] = excl; bcursor[t] = excl; }
    if (t == NB - 1) bbase[NB] = s[t];  // = E
}

// ---------------- C: scatter (src,dst) pairs into bucket-grouped tmp ----------------
__global__ __launch_bounds__(256) void bucket_scatter(const int* __restrict__ src,
                                                      const int* __restrict__ dst, int E,
                                                      int NB, int* __restrict__ bcursor,
                                                      int2* __restrict__ tmp) {
    __shared__ int lh[MAXB];
    __shared__ int lbase[MAXB];
    int t = threadIdx.x;
    for (int i = t; i < NB; i += 256) lh[i] = 0;
    __syncthreads();
    int base = blockIdx.x * CHUNK;
    int end = min(base + CHUNK, E);
    for (int i = base + t; i < end; i += 256)
        atomicAdd(&lh[dst[i] >> 8], 1);
    __syncthreads();
    for (int i = t; i < NB; i += 256) {
        int v = lh[i];
        lbase[i] = v ? atomicAdd(&bcursor[i], v) : 0;
        lh[i] = 0;  // reuse as local cursor
    }
    __syncthreads();
    for (int i = base + t; i < end; i += 256) {
        int s_ = src[i], d_ = dst[i];
        int b = d_ >> 8;
        int p = lbase[b] + atomicAdd(&lh[b], 1);
        tmp[p] = make_int2(s_, d_);
    }
}

// ---------------- D: per-bucket finalize: local CSR + dinv + srcs ----------------
__global__ __launch_bounds__(256) void bucket_finalize(const int2* __restrict__ tmp,
                                                       const int* __restrict__ bbase,
                                                       int n, int E, int NB,
                                                       int* __restrict__ offsets,
                                                       float* __restrict__ dinv,
                                                       int* __restrict__ srcs) {
    int b = blockIdx.x;
    int t = threadIdx.x;
    __shared__ int ldeg[256];
    __shared__ int lsc[256];
    __shared__ int lcur[256];
    ldeg[t] = 0;
    __syncthreads();
    int s0 = bbase[b], e0 = bbase[b + 1];
    for (int e = s0 + t; e < e0; e += 256)
        atomicAdd(&ldeg[tmp[e].y & 255], 1);
    __syncthreads();
    int v = ldeg[t];
    lsc[t] = v;
    __syncthreads();
    for (int o = 1; o < 256; o <<= 1) {
        int x = (t >= o) ? lsc[t - o] : 0;
        __syncthreads();
        lsc[t] += x;
        __syncthreads();
    }
    int excl = lsc[t] - v;
    lcur[t] = excl;
    int node = (b << 8) + t;
    if (node < n) {
        offsets[node] = s0 + excl;
        dinv[node] = rsqrtf((float)v + 1.0f);  // +1 self-loop
    }
    if (b == NB - 1 && t == 0) offsets[n] = E;
    __syncthreads();
    for (int e = s0 + t; e < e0; e += 256) {
        int2 r = tmp[e];
        int p = s0 + atomicAdd(&lcur[r.y & 255], 1);
        srcs[p] = r.x;
    }
}

// ---------------- GEMM: Yh[row,:] = half((X[row,:] @ W) * dscale[row]) ----------------
__global__ __launch_bounds__(256) void gemm64(const float* __restrict__ X,
                                              const float* __restrict__ W,
                                              const float* __restrict__ dscale,
                                              __half* __restrict__ Y, int n) {
    int lane = threadIdx.x & 63;
    int wv   = __builtin_amdgcn_readfirstlane(threadIdx.x >> 6);
    int row0 = blockIdx.x * (4 * RPW) + wv * RPW;

    float wk[NCH];
#pragma unroll
    for (int k = 0; k < NCH; ++k) wk[k] = W[k * NCH + lane];

#pragma unroll 1
    for (int j = 0; j < RPW; ++j) {
        int row = row0 + j;
        if (row >= n) break;
        const float4* xr = (const float4*)(X + (size_t)row * NCH);
        float a0 = 0.f, a1 = 0.f, a2 = 0.f, a3 = 0.f;
#pragma unroll
        for (int kc = 0; kc < 16; kc += 4) {
            float4 v0 = xr[kc + 0];
            float4 v1 = xr[kc + 1];
            float4 v2 = xr[kc + 2];
            float4 v3 = xr[kc + 3];
            a0 += v0.x * wk[4*kc + 0] + v0.y * wk[4*kc + 1] + v0.z * wk[4*kc + 2] + v0.w * wk[4*kc + 3];
            a1 += v1.x * wk[4*kc + 4] + v1.y * wk[4*kc + 5] + v1.z * wk[4*kc + 6] + v1.w * wk[4*kc + 7];
            a2 += v2.x * wk[4*kc + 8] + v2.y * wk[4*kc + 9] + v2.z * wk[4*kc +10] + v2.w * wk[4*kc +11];
            a3 += v3.x * wk[4*kc +12] + v3.y * wk[4*kc +13] + v3.z * wk[4*kc +14] + v3.w * wk[4*kc +15];
        }
        float a = (a0 + a1) + (a2 + a3);
        Y[(size_t)row * NCH + lane] = __float2half(a * dscale[row]);
    }
}

// ---------------- CSR gather (fp16 table) + self-loop + bias + relu ----------------
__global__ __launch_bounds__(256) void gather_fused(const __half* __restrict__ XWs,
                                                    const int* __restrict__ srcs,
                                                    const int* __restrict__ offsets,
                                                    const float* __restrict__ dinv,
                                                    const float* __restrict__ b,
                                                    float* __restrict__ H, int n) {
    int wid  = (int)((blockIdx.x * (size_t)blockDim.x + threadIdx.x) >> 6);  // node
    int lane = threadIdx.x & 63;                                             // channel
    if (wid >= n) return;
    int start = offsets[wid], end = offsets[wid + 1];
    float acc0 = __half2float(XWs[wid * NCH + lane]);  // self-loop (already *dinv[wid])
    float acc1 = 0.f, acc2 = 0.f, acc3 = 0.f;
    int e = start;
    for (; e + 4 <= end; e += 4) {
        int s0 = srcs[e], s1 = srcs[e + 1], s2 = srcs[e + 2], s3 = srcs[e + 3];
        acc0 += __half2float(XWs[s0 * NCH + lane]);
        acc1 += __half2float(XWs[s1 * NCH + lane]);
        acc2 += __half2float(XWs[s2 * NCH + lane]);
        acc3 += __half2float(XWs[s3 * NCH + lane]);
    }
    for (; e < end; ++e) {
        int s0 = srcs[e];
        acc0 += __half2float(XWs[s0 * NCH + lane]);
    }
    float v = (acc0 + acc1) + (acc2 + acc3);
    v = v * dinv[wid] + b[lane];
    H[(size_t)wid * NCH + lane] = v > 0.0f ? v : 0.0f;
}

// ---------------- pool stage 1: per-wave contiguous slice -> atomic flush per graph-run ----
__global__ __launch_bounds__(256) void pool_partial(const float* __restrict__ H,
                                                    const int* __restrict__ batch, int n,
                                                    float* __restrict__ pooled) {
    int gwave = blockIdx.x * 4 + (threadIdx.x >> 6);
    int lane  = threadIdx.x & 63;
    int nwaves = POOL_BLOCKS * 4;
    int per = (n + nwaves - 1) / nwaves;
    int start = gwave * per;
    int end = min(start + per, n);
    if (start >= end) return;
    int cur = batch[start];
    float acc = 0.f;
    for (int i = start; i < end; ++i) {
        int g = batch[i];
        if (g != cur) {
            atomicAdd(&pooled[cur * NCH + lane], acc);
            acc = 0.f;
            cur = g;
        }
        acc += H[(size_t)i * NCH + lane];
    }
    atomicAdd(&pooled[cur * NCH + lane], acc);
}

// ---------------- pool stage 2: mean + FC + relu (one wave per graph) ----------------
__global__ __launch_bounds__(64) void fc_out(const float* __restrict__ pooled,
                                             const int* __restrict__ batch, int n,
                                             const float* __restrict__ Wfc,
                                             const float* __restrict__ bfc,
                                             float* __restrict__ out) {
    int g = blockIdx.x;
    int c = threadIdx.x;
    int lo = 0, hi = n;
    while (lo < hi) { int m = (lo + hi) >> 1; if (batch[m] < g) lo = m + 1; else hi = m; }
    int start = lo;
    hi = n;
    while (lo < hi) { int m = (lo + hi) >> 1; if (batch[m] < g + 1) lo = m + 1; else hi = m; }
    int count = lo - start;

    __shared__ float ps[64];
    float inv = 1.0f / (float)(count > 1 ? count : 1);
    ps[c] = pooled[g * NCH + c] * inv;
    __syncthreads();
    float acc = bfc[c];
#pragma unroll
    for (int k = 0; k < 64; ++k) acc += ps[k] * Wfc[k * NCH + c];
    out[(size_t)g * NCH + c] = acc > 0.0f ? acc : 0.0f;
}

static inline size_t align256(size_t x) { return (x + 255) & ~(size_t)255; }

extern "C" void kernel_launch(void* const* d_in, const int* in_sizes, int n_in,
                              void* d_out, int out_size, void* d_ws, size_t ws_size,
                              hipStream_t stream) {
    const float* x     = (const float*)d_in[0];
    const int*   ei    = (const int*)d_in[1];
    const int*   batch = (const int*)d_in[2];
    const float* W1    = (const float*)d_in[3];
    const float* b1    = (const float*)d_in[4];
    const float* W2    = (const float*)d_in[5];
    const float* b2    = (const float*)d_in[6];
    const float* Wfc   = (const float*)d_in[7];
    const float* bfc   = (const float*)d_in[8];
    float* out = (float*)d_out;

    int E = in_sizes[1] / 2;
    int n = in_sizes[0] / NCH;
    int ngraphs = out_size / NCH;
    const int* src = ei;
    const int* dst = ei + E;
    int NB = (n + 255) >> 8;

    char* p = (char*)d_ws;
    int*    bhist   = (int*)p;    p += align256((size_t)(MAXB + 1) * 4);
    int*    bbase   = (int*)p;    p += align256((size_t)(MAXB + 1) * 4);
    int*    bcursor = (int*)p;    p += align256((size_t)MAXB * 4);
    int*    offsets = (int*)p;    p += align256((size_t)(n + 1) * 4);
    float*  dinv    = (float*)p;  p += align256((size_t)n * 4);
    float*  pooled  = (float*)p;  p += align256((size_t)ngraphs * NCH * 4);
    int2*   tmp     = (int2*)p;   p += align256((size_t)E * 8);
    int*    srcs    = (int*)p;    p += align256((size_t)E * 4);
    __half* xwh     = (__half*)p; p += align256((size_t)n * NCH * 2);
    float*  h       = (float*)p;

    int eblocks = (E + CHUNK - 1) / CHUNK;

    // ---- CSR build via 2-level bucket sort (shared by both layers) ----
    hipMemsetAsync(bhist, 0, (size_t)NB * sizeof(int), stream);
    hipMemsetAsync(pooled, 0, (size_t)ngraphs * NCH * sizeof(float), stream);
    bucket_hist<<<eblocks, 256, 0, stream>>>(dst, E, NB, bhist);
    bucket_scan<<<1, MAXB, 0, stream>>>(bhist, NB, bbase, bcursor);
    bucket_scatter<<<eblocks, 256, 0, stream>>>(src, dst, E, NB, bcursor, tmp);
    bucket_finalize<<<NB, 256, 0, stream>>>(tmp, bbase, n, E, NB, offsets, dinv, srcs);

    int rows_per_block = 4 * RPW;  // 32
    int gemm_blocks = (n + rows_per_block - 1) / rows_per_block;

    // ---- layer 1 ----
    gemm64<<<gemm_blocks, 256, 0, stream>>>(x, W1, dinv, xwh, n);
    gather_fused<<<(n * NCH + 255) / 256, 256, 0, stream>>>(xwh, srcs, offsets, dinv, b1, h, n);

    // ---- layer 2 ----
    gemm64<<<gemm_blocks, 256, 0, stream>>>(h, W2, dinv, xwh, n);
    gather_fused<<<(n * NCH + 255) / 256, 256, 0, stream>>>(xwh, srcs, offsets, dinv, b2, h, n);

    // ---- pool + fc ----
    pool_partial<<<POOL_BLOCKS, 256, 0, stream>>>(h, batch, n, pooled);
    fc_out<<<ngraphs, 64, 0, stream>>>(pooled, batch, n, Wfc, bfc, out);
}

// Round 10
// 310.052 us; speedup vs baseline: 4.3732x; 1.0604x over previous
//
#include <hip/hip_runtime.h>
#include <hip/hip_fp16.h>
#include <type_traits>

#define NCH 64
#define MAXB 512   // max buckets (supports n <= 131072)
#define CHUNK 4096 // edges per block in hist/scatter
#define POOL_BLOCKS 2048

// ---------------- A: bucket histogram (bucket = dst >> 8) ----------------
__global__ __launch_bounds__(256) void bucket_hist(const int* __restrict__ dst, int E,
                                                   int NB, int* __restrict__ bhist) {
    __shared__ int lh[MAXB];
    int t = threadIdx.x;
    for (int i = t; i < NB; i += 256) lh[i] = 0;
    __syncthreads();
    int base = blockIdx.x * CHUNK;
    int end = min(base + CHUNK, E);
    for (int i = base + t; i < end; i += 256)
        atomicAdd(&lh[dst[i] >> 8], 1);
    __syncthreads();
    for (int i = t; i < NB; i += 256) {
        int v = lh[i];
        if (v) atomicAdd(&bhist[i], v);
    }
}

// ---------------- B: exclusive scan of bucket counts (1 block) ----------------
__global__ __launch_bounds__(MAXB) void bucket_scan(const int* __restrict__ bhist, int NB,
                                                    int* __restrict__ bbase,
                                                    int* __restrict__ bcursor) {
    __shared__ int s[MAXB];
    int t = threadIdx.x;
    int v = (t < NB) ? bhist[t] : 0;
    s[t] = v;
    __syncthreads();
    for (int o = 1; o < MAXB; o <<= 1) {
        int x = (t >= o) ? s[t - o] : 0;
        __syncthreads();
        s[t] += x;
        __syncthreads();
    }
    int excl = s[t] - v;
    if (t < NB) { bbase[t] = excl; bcursor[t] = excl; }
    if (t == NB - 1) bbase[NB] = s[t];  // = E
}

// ---------------- C: scatter packed (src<<8 | dst&255) into bucket-grouped tmp ----------
__global__ __launch_bounds__(256) void bucket_scatter(const int* __restrict__ src,
                                                      const int* __restrict__ dst, int E,
                                                      int NB, int* __restrict__ bcursor,
                                                      int* __restrict__ tmp) {
    __shared__ int lh[MAXB];
    __shared__ int lbase[MAXB];
    int t = threadIdx.x;
    for (int i = t; i < NB; i += 256) lh[i] = 0;
    __syncthreads();
    int base = blockIdx.x * CHUNK;
    int end = min(base + CHUNK, E);
    for (int i = base + t; i < end; i += 256)
        atomicAdd(&lh[dst[i] >> 8], 1);
    __syncthreads();
    for (int i = t; i < NB; i += 256) {
        int v = lh[i];
        lbase[i] = v ? atomicAdd(&bcursor[i], v) : 0;
        lh[i] = 0;  // reuse as local cursor
    }
    __syncthreads();
    for (int i = base + t; i < end; i += 256) {
        int s_ = src[i], d_ = dst[i];
        int b = d_ >> 8;
        int p = lbase[b] + atomicAdd(&lh[b], 1);
        tmp[p] = (s_ << 8) | (d_ & 255);
    }
}

// ---------------- D: per-bucket finalize: local CSR + dinv + srcs ----------------
__global__ __launch_bounds__(256) void bucket_finalize(const int* __restrict__ tmp,
                                                       const int* __restrict__ bbase,
                                                       int n, int E, int NB,
                                                       int* __restrict__ offsets,
                                                       float* __restrict__ dinv,
                                                       int* __restrict__ srcs) {
    int b = blockIdx.x;
    int t = threadIdx.x;
    __shared__ int ldeg[256];
    __shared__ int lsc[256];
    __shared__ int lcur[256];
    ldeg[t] = 0;
    __syncthreads();
    int s0 = bbase[b], e0 = bbase[b + 1];
    for (int e = s0 + t; e < e0; e += 256)
        atomicAdd(&ldeg[tmp[e] & 255], 1);
    __syncthreads();
    int v = ldeg[t];
    lsc[t] = v;
    __syncthreads();
    for (int o = 1; o < 256; o <<= 1) {
        int x = (t >= o) ? lsc[t - o] : 0;
        __syncthreads();
        lsc[t] += x;
        __syncthreads();
    }
    int excl = lsc[t] - v;
    lcur[t] = excl;
    int node = (b << 8) + t;
    if (node < n) {
        offsets[node] = s0 + excl;
        dinv[node] = rsqrtf((float)v + 1.0f);  // +1 self-loop
    }
    if (b == NB - 1 && t == 0) offsets[n] = E;
    __syncthreads();
    for (int e = s0 + t; e < e0; e += 256) {
        int r = tmp[e];
        int p = s0 + atomicAdd(&lcur[r & 255], 1);
        srcs[p] = (int)(((unsigned)r) >> 8);
    }
}

// ---------------- GEMM: Yh[row,:] = half((X[row,:] @ W) * dscale[row]) ----------------
// 64-row tile staged in LDS (coalesced per-lane loads), W columns in registers,
// compute via LDS broadcast reads. 4 waves/block, 16 rows/wave.
template <typename T>
__global__ __launch_bounds__(256) void gemm64(const T* __restrict__ X,
                                              const float* __restrict__ W,
                                              const float* __restrict__ dscale,
                                              __half* __restrict__ Y, int n) {
    __shared__ float Xs[64][64];  // 16 KB
    int tid = threadIdx.x, lane = tid & 63, wv = tid >> 6;
    int row0 = blockIdx.x * 64;

    float wk[NCH];
#pragma unroll
    for (int k = 0; k < NCH; ++k) wk[k] = W[k * NCH + lane];

    if constexpr (std::is_same_v<T, float>) {
        const float4* X4 = (const float4*)(X + (size_t)row0 * NCH);
        float4* Xs4 = (float4*)Xs;
#pragma unroll
        for (int i = 0; i < 4; ++i) {
            int idx = tid + 256 * i;       // float4 index; 16 per row
            int r = idx >> 4;
            float4 v = make_float4(0.f, 0.f, 0.f, 0.f);
            if (row0 + r < n) v = X4[idx];
            Xs4[idx] = v;
        }
    } else {
        const float4* H16 = (const float4*)(X + (size_t)row0 * NCH);  // 8 halves per float4
#pragma unroll
        for (int i = 0; i < 2; ++i) {
            int idx = tid + 256 * i;       // half8 index; 8 per row
            int r = idx >> 3;
            int c0 = (idx & 7) * 8;
            float4 raw = make_float4(0.f, 0.f, 0.f, 0.f);
            if (row0 + r < n) raw = H16[idx];
            const __half2* hp = (const __half2*)&raw;
            float2 f0 = __half22float2(hp[0]);
            float2 f1 = __half22float2(hp[1]);
            float2 f2 = __half22float2(hp[2]);
            float2 f3 = __half22float2(hp[3]);
            float4 lo = make_float4(f0.x, f0.y, f1.x, f1.y);
            float4 hi = make_float4(f2.x, f2.y, f3.x, f3.y);
            *(float4*)&Xs[r][c0]     = lo;
            *(float4*)&Xs[r][c0 + 4] = hi;
        }
    }
    __syncthreads();

#pragma unroll 2
    for (int j = 0; j < 16; ++j) {
        int r = (wv << 4) + j;
        int row = row0 + r;
        if (row >= n) break;
        float a0 = 0.f, a1 = 0.f, a2 = 0.f, a3 = 0.f;
#pragma unroll
        for (int kc = 0; kc < 64; kc += 16) {
            float4 v0 = *(const float4*)&Xs[r][kc + 0];
            float4 v1 = *(const float4*)&Xs[r][kc + 4];
            float4 v2 = *(const float4*)&Xs[r][kc + 8];
            float4 v3 = *(const float4*)&Xs[r][kc + 12];
            a0 += v0.x * wk[kc + 0] + v0.y * wk[kc + 1] + v0.z * wk[kc + 2] + v0.w * wk[kc + 3];
            a1 += v1.x * wk[kc + 4] + v1.y * wk[kc + 5] + v1.z * wk[kc + 6] + v1.w * wk[kc + 7];
            a2 += v2.x * wk[kc + 8] + v2.y * wk[kc + 9] + v2.z * wk[kc +10] + v2.w * wk[kc +11];
            a3 += v3.x * wk[kc +12] + v3.y * wk[kc +13] + v3.z * wk[kc +14] + v3.w * wk[kc +15];
        }
        float a = (a0 + a1) + (a2 + a3);
        Y[(size_t)row * NCH + lane] = __float2half(a * dscale[row]);
    }
}

// ---------------- CSR gather (fp16 table) + self-loop + bias + relu -> fp16 H ----------
__global__ __launch_bounds__(256) void gather_fused(const __half* __restrict__ XWs,
                                                    const int* __restrict__ srcs,
                                                    const int* __restrict__ offsets,
                                                    const float* __restrict__ dinv,
                                                    const float* __restrict__ b,
                                                    __half* __restrict__ H, int n) {
    int wid  = (int)((blockIdx.x * (size_t)blockDim.x + threadIdx.x) >> 6);  // node
    int lane = threadIdx.x & 63;                                             // channel
    if (wid >= n) return;
    int start = offsets[wid], end = offsets[wid + 1];
    float acc0 = __half2float(XWs[(size_t)wid * NCH + lane]);  // self-loop
    float acc1 = 0.f, acc2 = 0.f, acc3 = 0.f;
    int e = start;
    for (; e + 8 <= end; e += 8) {
        int s0 = srcs[e],     s1 = srcs[e + 1], s2 = srcs[e + 2], s3 = srcs[e + 3];
        int s4 = srcs[e + 4], s5 = srcs[e + 5], s6 = srcs[e + 6], s7 = srcs[e + 7];
        acc0 += __half2float(XWs[(size_t)s0 * NCH + lane]);
        acc1 += __half2float(XWs[(size_t)s1 * NCH + lane]);
        acc2 += __half2float(XWs[(size_t)s2 * NCH + lane]);
        acc3 += __half2float(XWs[(size_t)s3 * NCH + lane]);
        acc0 += __half2float(XWs[(size_t)s4 * NCH + lane]);
        acc1 += __half2float(XWs[(size_t)s5 * NCH + lane]);
        acc2 += __half2float(XWs[(size_t)s6 * NCH + lane]);
        acc3 += __half2float(XWs[(size_t)s7 * NCH + lane]);
    }
    for (; e + 2 <= end; e += 2) {
        int s0 = srcs[e], s1 = srcs[e + 1];
        acc0 += __half2float(XWs[(size_t)s0 * NCH + lane]);
        acc1 += __half2float(XWs[(size_t)s1 * NCH + lane]);
    }
    if (e < end) {
        int s0 = srcs[e];
        acc2 += __half2float(XWs[(size_t)s0 * NCH + lane]);
    }
    float v = (acc0 + acc1) + (acc2 + acc3);
    v = v * dinv[wid] + b[lane];
    H[(size_t)wid * NCH + lane] = __float2half(v > 0.0f ? v : 0.0f);
}

// ---------------- pool stage 1: per-wave contiguous slice -> atomic flush per run -------
__global__ __launch_bounds__(256) void pool_partial(const __half* __restrict__ H,
                                                    const int* __restrict__ batch, int n,
                                                    float* __restrict__ pooled) {
    int gwave = blockIdx.x * 4 + (threadIdx.x >> 6);
    int lane  = threadIdx.x & 63;
    int nwaves = POOL_BLOCKS * 4;
    int per = (n + nwaves - 1) / nwaves;
    int start = gwave * per;
    int end = min(start + per, n);
    if (start >= end) return;
    int cur = batch[start];
    float acc = 0.f;
    for (int i = start; i < end; ++i) {
        int g = batch[i];
        if (g != cur) {
            atomicAdd(&pooled[cur * NCH + lane], acc);
            acc = 0.f;
            cur = g;
        }
        acc += __half2float(H[(size_t)i * NCH + lane]);
    }
    atomicAdd(&pooled[cur * NCH + lane], acc);
}

// ---------------- pool stage 2: mean + FC + relu (one wave per graph) ----------------
__global__ __launch_bounds__(64) void fc_out(const float* __restrict__ pooled,
                                             const int* __restrict__ batch, int n,
                                             const float* __restrict__ Wfc,
                                             const float* __restrict__ bfc,
                                             float* __restrict__ out) {
    int g = blockIdx.x;
    int c = threadIdx.x;
    int lo = 0, hi = n;
    while (lo < hi) { int m = (lo + hi) >> 1; if (batch[m] < g) lo = m + 1; else hi = m; }
    int start = lo;
    hi = n;
    while (lo < hi) { int m = (lo + hi) >> 1; if (batch[m] < g + 1) lo = m + 1; else hi = m; }
    int count = lo - start;

    __shared__ float ps[64];
    float inv = 1.0f / (float)(count > 1 ? count : 1);
    ps[c] = pooled[g * NCH + c] * inv;
    __syncthreads();
    float acc = bfc[c];
#pragma unroll
    for (int k = 0; k < 64; ++k) acc += ps[k] * Wfc[k * NCH + c];
    out[(size_t)g * NCH + c] = acc > 0.0f ? acc : 0.0f;
}

static inline size_t align256(size_t x) { return (x + 255) & ~(size_t)255; }

extern "C" void kernel_launch(void* const* d_in, const int* in_sizes, int n_in,
                              void* d_out, int out_size, void* d_ws, size_t ws_size,
                              hipStream_t stream) {
    const float* x     = (const float*)d_in[0];
    const int*   ei    = (const int*)d_in[1];
    const int*   batch = (const int*)d_in[2];
    const float* W1    = (const float*)d_in[3];
    const float* b1    = (const float*)d_in[4];
    const float* W2    = (const float*)d_in[5];
    const float* b2    = (const float*)d_in[6];
    const float* Wfc   = (const float*)d_in[7];
    const float* bfc   = (const float*)d_in[8];
    float* out = (float*)d_out;

    int E = in_sizes[1] / 2;
    int n = in_sizes[0] / NCH;
    int ngraphs = out_size / NCH;
    const int* src = ei;
    const int* dst = ei + E;
    int NB = (n + 255) >> 8;

    char* p = (char*)d_ws;
    int*    bhist   = (int*)p;    p += align256((size_t)(MAXB + 1) * 4);
    int*    bbase   = (int*)p;    p += align256((size_t)(MAXB + 1) * 4);
    int*    bcursor = (int*)p;    p += align256((size_t)MAXB * 4);
    int*    offsets = (int*)p;    p += align256((size_t)(n + 1) * 4);
    float*  dinv    = (float*)p;  p += align256((size_t)n * 4);
    float*  pooled  = (float*)p;  p += align256((size_t)ngraphs * NCH * 4);
    int*    tmp     = (int*)p;    p += align256((size_t)E * 4);
    int*    srcs    = (int*)p;    p += align256((size_t)E * 4);
    __half* xwh     = (__half*)p; p += align256((size_t)n * NCH * 2);
    __half* h       = (__half*)p;

    int eblocks = (E + CHUNK - 1) / CHUNK;

    // ---- CSR build via 2-level bucket sort (shared by both layers) ----
    hipMemsetAsync(bhist, 0, (size_t)NB * sizeof(int), stream);
    hipMemsetAsync(pooled, 0, (size_t)ngraphs * NCH * sizeof(float), stream);
    bucket_hist<<<eblocks, 256, 0, stream>>>(dst, E, NB, bhist);
    bucket_scan<<<1, MAXB, 0, stream>>>(bhist, NB, bbase, bcursor);
    bucket_scatter<<<eblocks, 256, 0, stream>>>(src, dst, E, NB, bcursor, tmp);
    bucket_finalize<<<NB, 256, 0, stream>>>(tmp, bbase, n, E, NB, offsets, dinv, srcs);

    int gemm_blocks = (n + 63) / 64;

    // ---- layer 1 ----
    gemm64<float><<<gemm_blocks, 256, 0, stream>>>(x, W1, dinv, xwh, n);
    gather_fused<<<(n * NCH + 255) / 256, 256, 0, stream>>>(xwh, srcs, offsets, dinv, b1, h, n);

    // ---- layer 2 ----
    gemm64<__half><<<gemm_blocks, 256, 0, stream>>>(h, W2, dinv, xwh, n);
    gather_fused<<<(n * NCH + 255) / 256, 256, 0, stream>>>(xwh, srcs, offsets, dinv, b2, h, n);

    // ---- pool + fc ----
    pool_partial<<<POOL_BLOCKS, 256, 0, stream>>>(h, batch, n, pooled);
    fc_out<<<ngraphs, 64, 0, stream>>>(pooled, batch, n, Wfc, bfc, out);
}

// Round 12
// 277.180 us; speedup vs baseline: 4.8918x; 1.1186x over previous
//
#include <hip/hip_runtime.h>
#include <hip/hip_fp16.h>
#include <type_traits>

#define NCH 64
#define MAXB 512   // max buckets (supports n <= 131072)
#define CHUNK 4096 // edges per block in hist/scatter
#define POOL_BLOCKS 2048

typedef _Float16 half8 __attribute__((ext_vector_type(8)));
typedef float floatx4 __attribute__((ext_vector_type(4)));

// ---------------- A: bucket histogram (bucket = dst >> 8) ----------------
__global__ __launch_bounds__(256) void bucket_hist(const int* __restrict__ dst, int E,
                                                   int NB, int* __restrict__ bhist) {
    __shared__ int lh[MAXB];
    int t = threadIdx.x;
    for (int i = t; i < NB; i += 256) lh[i] = 0;
    __syncthreads();
    int base = blockIdx.x * CHUNK;
    int end = min(base + CHUNK, E);
    for (int i = base + t; i < end; i += 256)
        atomicAdd(&lh[dst[i] >> 8], 1);
    __syncthreads();
    for (int i = t; i < NB; i += 256) {
        int v = lh[i];
        if (v) atomicAdd(&bhist[i], v);
    }
}

// ---------------- B: exclusive scan of bucket counts (1 block) ----------------
__global__ __launch_bounds__(MAXB) void bucket_scan(const int* __restrict__ bhist, int NB,
                                                    int* __restrict__ bbase,
                                                    int* __restrict__ bcursor) {
    __shared__ int s[MAXB];
    int t = threadIdx.x;
    int v = (t < NB) ? bhist[t] : 0;
    s[t] = v;
    __syncthreads();
    for (int o = 1; o < MAXB; o <<= 1) {
        int x = (t >= o) ? s[t - o] : 0;
        __syncthreads();
        s[t] += x;
        __syncthreads();
    }
    int excl = s[t] - v;
    if (t < NB) { bbase[t] = excl; bcursor[t] = excl; }
    if (t == NB - 1) bbase[NB] = s[t];  // = E
}

// ---------------- C: scatter packed (src<<8 | dst&255) into bucket-grouped tmp ----------
__global__ __launch_bounds__(256) void bucket_scatter(const int* __restrict__ src,
                                                      const int* __restrict__ dst, int E,
                                                      int NB, int* __restrict__ bcursor,
                                                      int* __restrict__ tmp) {
    __shared__ int lh[MAXB];
    __shared__ int lbase[MAXB];
    int t = threadIdx.x;
    for (int i = t; i < NB; i += 256) lh[i] = 0;
    __syncthreads();
    int base = blockIdx.x * CHUNK;
    int end = min(base + CHUNK, E);
    for (int i = base + t; i < end; i += 256)
        atomicAdd(&lh[dst[i] >> 8], 1);
    __syncthreads();
    for (int i = t; i < NB; i += 256) {
        int v = lh[i];
        lbase[i] = v ? atomicAdd(&bcursor[i], v) : 0;
        lh[i] = 0;  // reuse as local cursor
    }
    __syncthreads();
    for (int i = base + t; i < end; i += 256) {
        int s_ = src[i], d_ = dst[i];
        int b = d_ >> 8;
        int p = lbase[b] + atomicAdd(&lh[b], 1);
        tmp[p] = (s_ << 8) | (d_ & 255);
    }
}

// ---------------- D: per-bucket finalize: local CSR + dinv + srcs ----------------
__global__ __launch_bounds__(256) void bucket_finalize(const int* __restrict__ tmp,
                                                       const int* __restrict__ bbase,
                                                       int n, int E, int NB,
                                                       int* __restrict__ offsets,
                                                       float* __restrict__ dinv,
                                                       int* __restrict__ srcs) {
    int b = blockIdx.x;
    int t = threadIdx.x;
    __shared__ int ldeg[256];
    __shared__ int lsc[256];
    __shared__ int lcur[256];
    ldeg[t] = 0;
    __syncthreads();
    int s0 = bbase[b], e0 = bbase[b + 1];
    for (int e = s0 + t; e < e0; e += 256)
        atomicAdd(&ldeg[tmp[e] & 255], 1);
    __syncthreads();
    int v = ldeg[t];
    lsc[t] = v;
    __syncthreads();
    for (int o = 1; o < 256; o <<= 1) {
        int x = (t >= o) ? lsc[t - o] : 0;
        __syncthreads();
        lsc[t] += x;
        __syncthreads();
    }
    int excl = lsc[t] - v;
    lcur[t] = excl;
    int node = (b << 8) + t;
    if (node < n) {
        offsets[node] = s0 + excl;
        dinv[node] = rsqrtf((float)v + 1.0f);  // +1 self-loop
    }
    if (b == NB - 1 && t == 0) offsets[n] = E;
    __syncthreads();
    for (int e = s0 + t; e < e0; e += 256) {
        int r = tmp[e];
        int p = s0 + atomicAdd(&lcur[r & 255], 1);
        srcs[p] = (int)(((unsigned)r) >> 8);
    }
}

// ---------------- W transpose + fp16 convert: wt[c][k] = W[k][c] ----------------
__global__ __launch_bounds__(256) void convert_wt(const float* __restrict__ W,
                                                  _Float16* __restrict__ wt) {
    int idx = blockIdx.x * 256 + threadIdx.x;  // idx = k*64 + c
    if (idx < NCH * NCH) {
        int k = idx >> 6, c = idx & 63;
        wt[c * NCH + k] = (_Float16)W[idx];
    }
}

// ---------------- MFMA GEMM: Yh[row,:] = half((X[row,:] @ W) * dscale[row]) ----------------
// One wave per 16-row tile; 4 waves/block => 64 rows/block.
// A-frag (16x16x32 f16): lane l holds X[row0+(l&15)][k0+(l>>4)*8 + j], j=0..7
// B-frag: lane l holds W[k0+(l>>4)*8+j][c0+(l&15)] = wt[(c0+(l&15))*64 + k0+(l>>4)*8 + j]
// D: lane l reg i -> Y[row0+(l>>4)*4+i][c0+(l&15)]
template <typename T>
__global__ __launch_bounds__(256) void gemm64_mfma(const T* __restrict__ X,
                                                   const _Float16* __restrict__ wt,
                                                   const float* __restrict__ dscale,
                                                   __half* __restrict__ Y, int n) {
    int tid = threadIdx.x;
    int lane = tid & 63, wv = tid >> 6;
    int row0 = blockIdx.x * 64 + wv * 16;
    if (row0 >= n) return;

    int lrow = lane & 15;          // A row / B col / D col within tile
    int kgrp = (lane >> 4) * 8;    // k offset of this lane's 8 elements

    // B-frags: 4 col-tiles x 2 k-steps
    half8 bf[4][2];
#pragma unroll
    for (int ct = 0; ct < 4; ++ct) {
#pragma unroll
        for (int ks = 0; ks < 2; ++ks) {
            bf[ct][ks] = *(const half8*)(wt + (ct * 16 + lrow) * NCH + ks * 32 + kgrp);
        }
    }

    // A-frags: 2 k-steps
    int arow = row0 + lrow;
    half8 af[2];
    if constexpr (std::is_same_v<T, float>) {
        if (arow < n) {
#pragma unroll
            for (int ks = 0; ks < 2; ++ks) {
                const float4* xr = (const float4*)(X + (size_t)arow * NCH + ks * 32 + kgrp);
                float4 u0 = xr[0], u1 = xr[1];
                half8 a;
                a[0] = (_Float16)u0.x; a[1] = (_Float16)u0.y;
                a[2] = (_Float16)u0.z; a[3] = (_Float16)u0.w;
                a[4] = (_Float16)u1.x; a[5] = (_Float16)u1.y;
                a[6] = (_Float16)u1.z; a[7] = (_Float16)u1.w;
                af[ks] = a;
            }
        } else {
            af[0] = half8{}; af[1] = half8{};
        }
    } else {
        if (arow < n) {
#pragma unroll
            for (int ks = 0; ks < 2; ++ks)
                af[ks] = *(const half8*)((const _Float16*)X + (size_t)arow * NCH + ks * 32 + kgrp);
        } else {
            af[0] = half8{}; af[1] = half8{};
        }
    }

    floatx4 acc[4] = {floatx4{0,0,0,0}, floatx4{0,0,0,0}, floatx4{0,0,0,0}, floatx4{0,0,0,0}};
#pragma unroll
    for (int ks = 0; ks < 2; ++ks) {
#pragma unroll
        for (int ct = 0; ct < 4; ++ct) {
            acc[ct] = __builtin_amdgcn_mfma_f32_16x16x32_f16(af[ks], bf[ct][ks], acc[ct], 0, 0, 0);
        }
    }

    // scale rows + store fp16
    int rbase = row0 + (lane >> 4) * 4;
    float ds[4];
#pragma unroll
    for (int i = 0; i < 4; ++i) ds[i] = (rbase + i < n) ? dscale[rbase + i] : 0.f;
#pragma unroll
    for (int i = 0; i < 4; ++i) {
        int row = rbase + i;
        if (row < n) {
#pragma unroll
            for (int ct = 0; ct < 4; ++ct) {
                Y[(size_t)row * NCH + ct * 16 + lrow] = __float2half(acc[ct][i] * ds[i]);
            }
        }
    }
}

// ---------------- CSR gather (fp16 table) + self-loop + bias + relu -> fp16 H ----------
__global__ __launch_bounds__(256) void gather_fused(const __half* __restrict__ XWs,
                                                    const int* __restrict__ srcs,
                                                    const int* __restrict__ offsets,
                                                    const float* __restrict__ dinv,
                                                    const float* __restrict__ b,
                                                    __half* __restrict__ H, int n) {
    int wid  = (int)((blockIdx.x * (size_t)blockDim.x + threadIdx.x) >> 6);  // node
    int lane = threadIdx.x & 63;                                             // channel
    if (wid >= n) return;
    int start = offsets[wid], end = offsets[wid + 1];
    float acc0 = __half2float(XWs[(size_t)wid * NCH + lane]);  // self-loop
    float acc1 = 0.f, acc2 = 0.f, acc3 = 0.f;
    int e = start;
    for (; e + 8 <= end; e += 8) {
        int s0 = srcs[e],     s1 = srcs[e + 1], s2 = srcs[e + 2], s3 = srcs[e + 3];
        int s4 = srcs[e + 4], s5 = srcs[e + 5], s6 = srcs[e + 6], s7 = srcs[e + 7];
        acc0 += __half2float(XWs[(size_t)s0 * NCH + lane]);
        acc1 += __half2float(XWs[(size_t)s1 * NCH + lane]);
        acc2 += __half2float(XWs[(size_t)s2 * NCH + lane]);
        acc3 += __half2float(XWs[(size_t)s3 * NCH + lane]);
        acc0 += __half2float(XWs[(size_t)s4 * NCH + lane]);
        acc1 += __half2float(XWs[(size_t)s5 * NCH + lane]);
        acc2 += __half2float(XWs[(size_t)s6 * NCH + lane]);
        acc3 += __half2float(XWs[(size_t)s7 * NCH + lane]);
    }
    for (; e + 2 <= end; e += 2) {
        int s0 = srcs[e], s1 = srcs[e + 1];
        acc0 += __half2float(XWs[(size_t)s0 * NCH + lane]);
        acc1 += __half2float(XWs[(size_t)s1 * NCH + lane]);
    }
    if (e < end) {
        int s0 = srcs[e];
        acc2 += __half2float(XWs[(size_t)s0 * NCH + lane]);
    }
    float v = (acc0 + acc1) + (acc2 + acc3);
    v = v * dinv[wid] + b[lane];
    H[(size_t)wid * NCH + lane] = __float2half(v > 0.0f ? v : 0.0f);
}

// ---------------- pool stage 1: per-wave contiguous slice -> atomic flush per run -------
__global__ __launch_bounds__(256) void pool_partial(const __half* __restrict__ H,
                                                    const int* __restrict__ batch, int n,
                                                    float* __restrict__ pooled) {
    int gwave = blockIdx.x * 4 + (threadIdx.x >> 6);
    int lane  = threadIdx.x & 63;
    int nwaves = POOL_BLOCKS * 4;
    int per = (n + nwaves - 1) / nwaves;
    int start = gwave * per;
    int end = min(start + per, n);
    if (start >= end) return;
    int cur = batch[start];
    float acc = 0.f;
    for (int i = start; i < end; ++i) {
        int g = batch[i];
        if (g != cur) {
            atomicAdd(&pooled[cur * NCH + lane], acc);
            acc = 0.f;
            cur = g;
        }
        acc += __half2float(H[(size_t)i * NCH + lane]);
    }
    atomicAdd(&pooled[cur * NCH + lane], acc);
}

// ---------------- pool stage 2: mean + FC + relu (one wave per graph) ----------------
__global__ __launch_bounds__(64) void fc_out(const float* __restrict__ pooled,
                                             const int* __restrict__ batch, int n,
                                             const float* __restrict__ Wfc,
                                             const float* __restrict__ bfc,
                                             float* __restrict__ out) {
    int g = blockIdx.x;
    int c = threadIdx.x;
    int lo = 0, hi = n;
    while (lo < hi) { int m = (lo + hi) >> 1; if (batch[m] < g) lo = m + 1; else hi = m; }
    int start = lo;
    hi = n;
    while (lo < hi) { int m = (lo + hi) >> 1; if (batch[m] < g + 1) lo = m + 1; else hi = m; }
    int count = lo - start;

    __shared__ float ps[64];
    float inv = 1.0f / (float)(count > 1 ? count : 1);
    ps[c] = pooled[g * NCH + c] * inv;
    __syncthreads();
    float acc = bfc[c];
#pragma unroll
    for (int k = 0; k < 64; ++k) acc += ps[k] * Wfc[k * NCH + c];
    out[(size_t)g * NCH + c] = acc > 0.0f ? acc : 0.0f;
}

static inline size_t align256(size_t x) { return (x + 255) & ~(size_t)255; }

extern "C" void kernel_launch(void* const* d_in, const int* in_sizes, int n_in,
                              void* d_out, int out_size, void* d_ws, size_t ws_size,
                              hipStream_t stream) {
    const float* x     = (const float*)d_in[0];
    const int*   ei    = (const int*)d_in[1];
    const int*   batch = (const int*)d_in[2];
    const float* W1    = (const float*)d_in[3];
    const float* b1    = (const float*)d_in[4];
    const float* W2    = (const float*)d_in[5];
    const float* b2    = (const float*)d_in[6];
    const float* Wfc   = (const float*)d_in[7];
    const float* bfc   = (const float*)d_in[8];
    float* out = (float*)d_out;

    int E = in_sizes[1] / 2;
    int n = in_sizes[0] / NCH;
    int ngraphs = out_size / NCH;
    const int* src = ei;
    const int* dst = ei + E;
    int NB = (n + 255) >> 8;

    char* p = (char*)d_ws;
    int*      bhist   = (int*)p;      p += align256((size_t)(MAXB + 1) * 4);
    int*      bbase   = (int*)p;      p += align256((size_t)(MAXB + 1) * 4);
    int*      bcursor = (int*)p;      p += align256((size_t)MAXB * 4);
    int*      offsets = (int*)p;      p += align256((size_t)(n + 1) * 4);
    float*    dinv    = (float*)p;    p += align256((size_t)n * 4);
    float*    pooled  = (float*)p;    p += align256((size_t)ngraphs * NCH * 4);
    _Float16* wt1     = (_Float16*)p; p += align256((size_t)NCH * NCH * 2);
    _Float16* wt2     = (_Float16*)p; p += align256((size_t)NCH * NCH * 2);
    int*      tmp     = (int*)p;      p += align256((size_t)E * 4);
    int*      srcs    = (int*)p;      p += align256((size_t)E * 4);
    __half*   xwh     = (__half*)p;   p += align256((size_t)n * NCH * 2);
    __half*   h       = (__half*)p;

    int eblocks = (E + CHUNK - 1) / CHUNK;

    // ---- CSR build via 2-level bucket sort (shared by both layers) ----
    hipMemsetAsync(bhist, 0, (size_t)NB * sizeof(int), stream);
    hipMemsetAsync(pooled, 0, (size_t)ngraphs * NCH * sizeof(float), stream);
    convert_wt<<<16, 256, 0, stream>>>(W1, wt1);
    convert_wt<<<16, 256, 0, stream>>>(W2, wt2);
    bucket_hist<<<eblocks, 256, 0, stream>>>(dst, E, NB, bhist);
    bucket_scan<<<1, MAXB, 0, stream>>>(bhist, NB, bbase, bcursor);
    bucket_scatter<<<eblocks, 256, 0, stream>>>(src, dst, E, NB, bcursor, tmp);
    bucket_finalize<<<NB, 256, 0, stream>>>(tmp, bbase, n, E, NB, offsets, dinv, srcs);

    int gemm_blocks = (n + 63) / 64;

    // ---- layer 1 ----
    gemm64_mfma<float><<<gemm_blocks, 256, 0, stream>>>(x, wt1, dinv, xwh, n);
    gather_fused<<<(n * NCH + 255) / 256, 256, 0, stream>>>(xwh, srcs, offsets, dinv, b1, h, n);

    // ---- layer 2 ----
    gemm64_mfma<__half><<<gemm_blocks, 256, 0, stream>>>(h, wt2, dinv, xwh, n);
    gather_fused<<<(n * NCH + 255) / 256, 256, 0, stream>>>(xwh, srcs, offsets, dinv, b2, h, n);

    // ---- pool + fc ----
    pool_partial<<<POOL_BLOCKS, 256, 0, stream>>>(h, batch, n, pooled);
    fc_out<<<ngraphs, 64, 0, stream>>>(pooled, batch, n, Wfc, bfc, out);
}